// Round 15
// baseline (3021.298 us; speedup 1.0000x reference)
//
#include <hip/hip_runtime.h>

using bf16x8 = __attribute__((ext_vector_type(8))) __bf16;
using short8 = __attribute__((ext_vector_type(8))) short;
using u16x8  = __attribute__((ext_vector_type(8))) unsigned short;
using u16x4  = __attribute__((ext_vector_type(4))) unsigned short;
using f32x4  = __attribute__((ext_vector_type(4))) float;

#define DEVI __device__ __forceinline__

// ---------- helpers ----------
DEVI unsigned short f2bf(float f) {
  union { float f; unsigned u; } un; un.f = f;
  unsigned r = un.u + 0x7fffu + ((un.u >> 16) & 1u);   // RNE
  return (unsigned short)(r >> 16);
}

typedef const __attribute__((address_space(1))) void* gas1_t;
typedef __attribute__((address_space(3))) void* las3_t;

DEVI void gload16(const void* g, void* lds) {
  __builtin_amdgcn_global_load_lds(
      reinterpret_cast<gas1_t>(reinterpret_cast<unsigned long long>(g)),
      reinterpret_cast<las3_t>(static_cast<unsigned>(reinterpret_cast<unsigned long long>(lds))),
      16, 0, 0);
}

#define VMW(n) asm volatile("s_waitcnt vmcnt(" #n ")" ::: "memory")
#define LGK0   do { asm volatile("s_waitcnt lgkmcnt(0)" ::: "memory"); __builtin_amdgcn_sched_barrier(0); } while (0)
#define BARS   do { __builtin_amdgcn_s_barrier(); __builtin_amdgcn_sched_barrier(0); } while (0)

// ---------- transpose + f32->bf16 convert:  dst[n][k] = bf16(src[k][n]) ----------
__global__ void __launch_bounds__(256)
transpose_cvt(const float* __restrict__ src, unsigned short* __restrict__ dst,
              int K, int N, int Nrows, long srcStride, long dstStride) {
  src += (size_t)blockIdx.z * srcStride;
  dst += (size_t)blockIdx.z * dstStride;
  __shared__ float tile[32][33];
  const int n0 = blockIdx.x * 32, k0 = blockIdx.y * 32;
  const int tx = threadIdx.x & 31, ty = threadIdx.x >> 5;
#pragma unroll
  for (int i = 0; i < 4; ++i) {
    const int kk = ty + i * 8;
    const int n = n0 + tx;
    tile[kk][tx] = (n < N) ? src[(size_t)(k0 + kk) * N + n] : 0.f;
  }
  __syncthreads();
#pragma unroll
  for (int i = 0; i < 4; ++i) {
    const int nn = ty + i * 8;
    const int n = n0 + nn;
    if (n < Nrows) dst[(size_t)n * K + k0 + tx] = f2bf(tile[tx][nn]);
  }
}

// ---------- concat q/k/v biases per layer into [L][3072] ----------
__global__ void __launch_bounds__(256)
concat_bias(const float* __restrict__ bq, const float* __restrict__ bk,
            const float* __restrict__ bv, float* __restrict__ ob) {
  const int i = blockIdx.x * 256 + threadIdx.x;
  if (i >= 8 * 3072) return;
  const int l = i / 3072, c = i - l * 3072;
  float v;
  if (c < 1024)      v = bq[l * 1024 + c];
  else if (c < 2048) v = bk[l * 1024 + c - 1024];
  else               v = bv[l * 1024 + c - 2048];
  ob[i] = v;
}

// ---------- embedding: cond token + tok_emb gather + sincos PE -> x (f32) ----------
__global__ void __launch_bounds__(256)
embed_kernel(const int* __restrict__ idx, const float* __restrict__ clip,
             const float* __restrict__ tok_emb, const float* __restrict__ cond_w,
             const float* __restrict__ cond_b, float* __restrict__ x) {
  const int row = blockIdx.x;
  const int b = row / 52, t = row - b * 52;
  const int c0 = threadIdx.x * 4;
  float e[4];
  if (t == 0) {
    e[0] = cond_b[c0]; e[1] = cond_b[c0 + 1]; e[2] = cond_b[c0 + 2]; e[3] = cond_b[c0 + 3];
    for (int k = 0; k < 512; ++k) {
      const float cf = clip[b * 512 + k];
      const float4 wv = *(const float4*)&cond_w[k * 1024 + c0];
      e[0] += cf * wv.x; e[1] += cf * wv.y; e[2] += cf * wv.z; e[3] += cf * wv.w;
    }
  } else {
    const int tok = idx[b * 51 + t - 1];
    const float4 tv = *(const float4*)&tok_emb[(size_t)tok * 1024 + c0];
    e[0] = tv.x; e[1] = tv.y; e[2] = tv.z; e[3] = tv.w;
  }
  const float nl = -9.2103403719761836f / 1024.0f;   // -ln(10000)/C
#pragma unroll
  for (int j = 0; j < 4; ++j) {
    const int c = c0 + j;
    const float dv = expf((float)(c & ~1) * nl);
    const float ang = (float)t * dv;
    e[j] += (c & 1) ? cosf(ang) : sinf(ang);
  }
  float4 o; o.x = e[0]; o.y = e[1]; o.z = e[2]; o.w = e[3];
  *(float4*)&x[(size_t)row * 1024 + c0] = o;
}

// ---------- LayerNorm (plain): f32 in -> bf16 out ----------
__global__ void __launch_bounds__(256)
ln_kernel(const float* __restrict__ x, const float* __restrict__ w,
          const float* __restrict__ bsh, unsigned short* __restrict__ out) {
  const size_t row = blockIdx.x;
  const int tid = threadIdx.x;
  const float4 v = *(const float4*)&x[row * 1024 + tid * 4];
  float s1 = v.x + v.y + v.z + v.w;
  float s2 = v.x * v.x + v.y * v.y + v.z * v.z + v.w * v.w;
#pragma unroll
  for (int m = 1; m < 64; m <<= 1) { s1 += __shfl_xor(s1, m); s2 += __shfl_xor(s2, m); }
  __shared__ float red[8];
  const int wid = tid >> 6;
  if ((tid & 63) == 0) { red[wid] = s1; red[4 + wid] = s2; }
  __syncthreads();
  s1 = red[0] + red[1] + red[2] + red[3];
  s2 = red[4] + red[5] + red[6] + red[7];
  const float mean = s1 * (1.0f / 1024.0f);
  const float var  = s2 * (1.0f / 1024.0f) - mean * mean;
  const float rstd = rsqrtf(var + 1e-5f);
  const float4 wv = *(const float4*)&w[tid * 4];
  const float4 bv = *(const float4*)&bsh[tid * 4];
  ushort4 o;
  o.x = f2bf((v.x - mean) * rstd * wv.x + bv.x);
  o.y = f2bf((v.y - mean) * rstd * wv.y + bv.y);
  o.z = f2bf((v.z - mean) * rstd * wv.z + bv.z);
  o.w = f2bf((v.w - mean) * rstd * wv.w + bv.w);
  *(ushort4*)&out[row * 1024 + tid * 4] = o;
}

// ---------- fused residual-reduce + LayerNorm (for split-K partials) ----------
// x_new = x_old + fc_bias + sum_s partial_s ; writes x_new (f32) and LN(x_new) (bf16)
__global__ void __launch_bounds__(256)
ln_sum_kernel(const float* __restrict__ xold, const float* __restrict__ part,
              long pstride, int S, const float* __restrict__ fcb,
              const float* __restrict__ w, const float* __restrict__ bsh,
              float* __restrict__ xnew, unsigned short* __restrict__ hout) {
  const size_t row = blockIdx.x;
  const int tid = threadIdx.x;
  const float4 xv = *(const float4*)&xold[row * 1024 + tid * 4];
  const float4 bb = *(const float4*)&fcb[tid * 4];
  float e0 = xv.x + bb.x, e1 = xv.y + bb.y, e2 = xv.z + bb.z, e3 = xv.w + bb.w;
  for (int s = 0; s < S; ++s) {
    const float4 p = *(const float4*)&part[(size_t)s * pstride + row * 1024 + tid * 4];
    e0 += p.x; e1 += p.y; e2 += p.z; e3 += p.w;
  }
  float s1 = e0 + e1 + e2 + e3;
  float s2 = e0 * e0 + e1 * e1 + e2 * e2 + e3 * e3;
#pragma unroll
  for (int m = 1; m < 64; m <<= 1) { s1 += __shfl_xor(s1, m); s2 += __shfl_xor(s2, m); }
  __shared__ float red[8];
  const int wid = tid >> 6;
  if ((tid & 63) == 0) { red[wid] = s1; red[4 + wid] = s2; }
  __syncthreads();
  s1 = red[0] + red[1] + red[2] + red[3];
  s2 = red[4] + red[5] + red[6] + red[7];
  const float mean = s1 * (1.0f / 1024.0f);
  const float var  = s2 * (1.0f / 1024.0f) - mean * mean;
  const float rstd = rsqrtf(var + 1e-5f);
  float4 xo; xo.x = e0; xo.y = e1; xo.z = e2; xo.w = e3;
  *(float4*)&xnew[row * 1024 + tid * 4] = xo;
  const float4 wv = *(const float4*)&w[tid * 4];
  const float4 bv = *(const float4*)&bsh[tid * 4];
  ushort4 o;
  o.x = f2bf((e0 - mean) * rstd * wv.x + bv.x);
  o.y = f2bf((e1 - mean) * rstd * wv.y + bv.y);
  o.z = f2bf((e2 - mean) * rstd * wv.z + bv.z);
  o.w = f2bf((e3 - mean) * rstd * wv.w + bv.w);
  *(ushort4*)&hout[row * 1024 + tid * 4] = o;
}

// ---------- 256x256 GEMM, BK=64, 2 x 64 KB dbuf, 2 phases/tile (R12/R14, proven) ----------
// 512 threads (8 waves = 2M x 4N of 128x64). Stage unit U(t,ks) = A+B K-half (32 KB,
// 4 gloads/thread). Per phase: VMW(4) -> barrier -> issue U(t+1,ks) -> 12 ds_read ->
// lgkmcnt(0) -> 32 MFMA. colmajor: chunk walks rows within one W col-panel (for shapes
// where the A-panel set would thrash L2, e.g. fc2 K=4096: 6.5x2MB > 4MB; col-major
// keeps W (2MB) L2-resident and streams A read-once).
// EPI 0: bf16 out + bias ; 1: + GELU ; 4: f32 partial (K-slice z)
template <int EPI>
__global__ void __launch_bounds__(512, 2)
gemm256(const unsigned short* __restrict__ A, const unsigned short* __restrict__ WT,
        const float* __restrict__ bias, void* outp,
        int Kfull, int N, int k_len, int ny, int nz, int colmajor) {
  constexpr bool SWAP = (EPI == 0 || EPI == 1);
  __shared__ unsigned short smem[65536];                 // 128 KB, reused as C-stage
  const int tid = threadIdx.x;
  const int lane = tid & 63;
  const int wid = tid >> 6;                              // 0..7
  const int lrow = lane & 15, lkg = lane >> 4;
  const int wm = wid >> 2, wn = wid & 3;                 // 2 M-halves x 4 N-quarters

  // bijective XCD chunk swizzle (m204); traversal within chunk per colmajor flag
  const int nwg = gridDim.x;
  int bid = blockIdx.x;
  {
    const int q = nwg >> 3, r = nwg & 7;
    const int xcd = bid & 7, i = bid >> 3;
    bid = ((xcd < r) ? xcd * (q + 1) : r * (q + 1) + (xcd - r) * q) + i;
  }
  const int nxy = nwg / nz;
  const int z = bid / nxy;
  const int rem = bid - z * nxy;
  int xt, yt;
  if (colmajor) {                                        // W col-panel resident, A streams
    const int nx = nxy / ny;
    yt = rem / nx;
    xt = rem - yt * nx;
  } else {                                               // A row-panels resident, W streams
    xt = rem / ny;
    yt = rem - xt * ny;
  }
  const long m0 = (long)xt * 256;
  const long n0 = (long)yt * 256;
  const int kb = z * k_len;

  // per-thread staging sources: f_j = j*8 + wid, row r = lane&15, kgrp = lane>>4
  const unsigned short* aS[2];
  const unsigned short* bS[2];
#pragma unroll
  for (int j = 0; j < 2; ++j) {
    const int f = j * 8 + wid;
    aS[j] = A  + (m0 + f * 16 + lrow) * (long)Kfull + kb + lkg * 8;
    bS[j] = WT + (n0 + f * 16 + lrow) * (long)Kfull + kb + lkg * 8;
  }

  auto STU = [&](int t, int ks) {                        // one K-half of tile t (4 gloads)
    const int bo = (t & 1) * 32768;
    const long kt = (long)t * 64 + ks * 32;
    gload16(aS[0] + kt, smem + bo + ks * 8192 + wid * 512);
    gload16(aS[1] + kt, smem + bo + ks * 8192 + (8 + wid) * 512);
    gload16(bS[0] + kt, smem + bo + 16384 + ks * 8192 + wid * 512);
    gload16(bS[1] + kt, smem + bo + 16384 + ks * 8192 + (8 + wid) * 512);
  };

  f32x4 acc[8][4] = {};
  const int T = k_len >> 6;                              // k_len multiple of 64

  STU(0, 0); STU(0, 1);                                  // 8 gloads in flight

  for (int t = 0; t < T; ++t) {
    const int bo = (t & 1) * 32768;
    bf16x8 afr[8], bfr[4];
#pragma unroll
    for (int ks = 0; ks < 2; ++ks) {
      if (t + 1 < T || ks == 0) VMW(4);                  // own U(t,ks) loads done
      else                      VMW(0);                  // final half: drain
      BARS;                                              // all waves' U(t,ks) writes visible
      if (t + 1 < T) STU(t + 1, ks);                     // other buffer, readers done at t-1
#pragma unroll
      for (int m = 0; m < 8; ++m)
        afr[m] = *(const bf16x8*)&smem[bo + ks * 8192 + (wm * 8 + m) * 512 + lane * 8];
#pragma unroll
      for (int n = 0; n < 4; ++n)
        bfr[n] = *(const bf16x8*)&smem[bo + 16384 + ks * 8192 + (wn * 4 + n) * 512 + lane * 8];
      LGK0;
      __builtin_amdgcn_s_setprio(1);
#pragma unroll
      for (int m = 0; m < 8; ++m)
#pragma unroll
        for (int n = 0; n < 4; ++n) {
          if constexpr (SWAP)
            acc[m][n] = __builtin_amdgcn_mfma_f32_16x16x32_bf16(bfr[n], afr[m], acc[m][n], 0, 0, 0);
          else
            acc[m][n] = __builtin_amdgcn_mfma_f32_16x16x32_bf16(afr[m], bfr[n], acc[m][n], 0, 0, 0);
        }
      __builtin_amdgcn_s_setprio(0);
    }
  }
  __syncthreads();                                       // protect smem reuse as C-stage

  if constexpr (SWAP) {
    // lane holds C[row = wm*128 + m*16 + lrow][cols = wn*64 + n*16 + lkg*4 .. +3]
#pragma unroll
    for (int m = 0; m < 8; ++m) {
      const int row = wm * 128 + m * 16 + lrow;
      const unsigned rb = (unsigned)row * 512;
      const unsigned sw = (unsigned)(row & 7) << 4;
#pragma unroll
      for (int n = 0; n < 4; ++n) {
        const int colb = wn * 64 + n * 16 + lkg * 4;
        const float4 bv = *(const float4*)&bias[n0 + colb];
        float v0 = acc[m][n][0] + bv.x;
        float v1 = acc[m][n][1] + bv.y;
        float v2 = acc[m][n][2] + bv.z;
        float v3 = acc[m][n][3] + bv.w;
        if constexpr (EPI == 1) {
          v0 = 0.5f * v0 * (1.0f + erff(v0 * 0.70710678118654752f));
          v1 = 0.5f * v1 * (1.0f + erff(v1 * 0.70710678118654752f));
          v2 = 0.5f * v2 * (1.0f + erff(v2 * 0.70710678118654752f));
          v3 = 0.5f * v3 * (1.0f + erff(v3 * 0.70710678118654752f));
        }
        u16x4 o = { f2bf(v0), f2bf(v1), f2bf(v2), f2bf(v3) };
        *(u16x4*)((char*)smem + ((rb + colb * 2) ^ sw)) = o;
      }
    }
    __syncthreads();
    unsigned short* out = (unsigned short*)outp;
#pragma unroll
    for (int i = 0; i < 16; ++i) {
      const int idx = tid + i * 512;        // 16B chunk, 8192 total (256 rows x 32)
      const int row = idx >> 5, c32 = idx & 31;
      const unsigned byteoff = ((unsigned)row * 512 + (unsigned)c32 * 16) ^ ((unsigned)(row & 7) << 4);
      const u16x8 v = *(const u16x8*)((const char*)smem + byteoff);
      *(u16x8*)&out[(m0 + row) * (long)N + n0 + c32 * 8] = v;
    }
  } else {
    float* out = (float*)outp + (size_t)z * ((size_t)(nxy / ny) * 256) * N;
#pragma unroll
    for (int n = 0; n < 4; ++n) {
      const int col = (int)n0 + wn * 64 + n * 16 + lrow;
#pragma unroll
      for (int m = 0; m < 8; ++m) {
        const long rowb = m0 + wm * 128 + m * 16 + lkg * 4;
#pragma unroll
        for (int r = 0; r < 4; ++r)
          out[(rowb + r) * (long)N + col] = acc[m][n][r];
      }
    }
  }
}

// ---------- 128x128 GEMM (3 buffers, 48KB, depth-2) for the head ----------
// EPI 3: f32 out plain
template <int EPI>
__global__ void __launch_bounds__(256)
gemm128(const unsigned short* __restrict__ A, const unsigned short* __restrict__ WT,
        const float* __restrict__ bias, const float* res, void* outp,
        int Kfull, int N, int k_len, int ny, int nz) {
  __shared__ unsigned short smem[24576];                 // 48 KB
  const int tid = threadIdx.x;
  const int lane = tid & 63;
  const int wid = tid >> 6;
  const int lrow = lane & 15, lkg = lane >> 4;
  const int wr = wid >> 1, wc = wid & 1;

  const int nwg = gridDim.x;
  int bid = blockIdx.x;
  {
    const int q = nwg >> 3, r = nwg & 7;
    const int xcd = bid & 7, i = bid >> 3;
    bid = ((xcd < r) ? xcd * (q + 1) : r * (q + 1) + (xcd - r) * q) + i;
  }
  const int nxy = nwg / nz;
  const int z = bid / nxy;
  const int rem = bid - z * nxy;
  const int xt = rem / ny;
  const int yt = rem - xt * ny;
  const long m0 = (long)xt * 128;
  const long n0 = (long)yt * 128;
  const int kb = z * k_len;

  const unsigned short* a0 = A + (m0 + (wid * 2 + 0) * 16 + lrow) * (long)Kfull + kb + lkg * 8;
  const unsigned short* a1 = A + (m0 + (wid * 2 + 1) * 16 + lrow) * (long)Kfull + kb + lkg * 8;
  const unsigned short* b0 = WT + (n0 + (wid * 2 + 0) * 16 + lrow) * (long)Kfull + kb + lkg * 8;
  const unsigned short* b1 = WT + (n0 + (wid * 2 + 1) * 16 + lrow) * (long)Kfull + kb + lkg * 8;
  const int so0 = (wid * 2 + 0) * 512, so1 = (wid * 2 + 1) * 512;

  f32x4 acc[4][4] = {};
  const int T = k_len >> 5;

  auto STAGE = [&](int t) {
    const int boff = (t % 3) * 8192;
    const int kt = t * 32;
    gload16(a0 + kt, smem + boff + so0);
    gload16(a1 + kt, smem + boff + so1);
    gload16(b0 + kt, smem + boff + 4096 + so0);
    gload16(b1 + kt, smem + boff + 4096 + so1);
  };

  STAGE(0);
  STAGE(1);

  for (int t = 0; t < T; ++t) {
    if (t + 1 < T) asm volatile("s_waitcnt vmcnt(4)" ::: "memory");
    else           asm volatile("s_waitcnt vmcnt(0)" ::: "memory");
    __builtin_amdgcn_s_barrier();
    __builtin_amdgcn_sched_barrier(0);
    if (t + 2 < T) STAGE(t + 2);
    const int cb = (t % 3) * 8192;
    bf16x8 af[4], bf8[4];
#pragma unroll
    for (int m = 0; m < 4; ++m) af[m] = *(const bf16x8*)&smem[cb + (wr * 4 + m) * 512 + lane * 8];
#pragma unroll
    for (int n = 0; n < 4; ++n) bf8[n] = *(const bf16x8*)&smem[cb + 4096 + (wc * 4 + n) * 512 + lane * 8];
#pragma unroll
    for (int m = 0; m < 4; ++m)
#pragma unroll
      for (int n = 0; n < 4; ++n)
        acc[m][n] = __builtin_amdgcn_mfma_f32_16x16x32_bf16(af[m], bf8[n], acc[m][n], 0, 0, 0);
  }
  __syncthreads();

#pragma unroll
  for (int n = 0; n < 4; ++n) {
    const int col = (int)n0 + wc * 64 + n * 16 + lrow;
    const bool cv = col < N;
#pragma unroll
    for (int m = 0; m < 4; ++m) {
      const long rowb = m0 + wr * 64 + m * 16 + lkg * 4;
#pragma unroll
      for (int r = 0; r < 4; ++r) {
        if (cv) ((float*)outp)[(rowb + r) * (long)N + col] = acc[m][n][r];
      }
    }
  }
}

// ---------- fused causal attention, one block per (b, h) ----------
__global__ void __launch_bounds__(256)
attn_kernel(const unsigned short* __restrict__ qkv,   // [M][3072] bf16 (q|k|v)
            unsigned short* __restrict__ attno) {     // [M][1024] bf16
  __shared__ unsigned short qA[4096];
  __shared__ unsigned short kB[4096];
  __shared__ unsigned short vB[4096];
  __shared__ unsigned short pA[4096];
  const int bh = blockIdx.x;
  const int b = bh >> 4, h = bh & 15;
  const int tid = threadIdx.x;
  const int lane = tid & 63;
  const int wid = tid >> 6;
  const int lrow = lane & 15, lkg = lane >> 4;

  for (int i = tid; i < 512; i += 256) {
    const int row = i >> 3;
    const int dc = i & 7;
    short8 qv = {}, kv = {}, vv = {};
    if (row < 52) {
      const unsigned short* base = qkv + ((size_t)(b * 52 + row)) * 3072 + h * 64 + dc * 8;
      qv = *(const short8*)(base);
      kv = *(const short8*)(base + 1024);
      vv = *(const short8*)(base + 2048);
    }
    *(short8*)&qA[(row >> 4) * 1024 + dc * 128 + (row & 15) * 8] = qv;
    *(short8*)&kB[(row >> 4) * 1024 + dc * 128 + (row & 15) * 8] = kv;
#pragma unroll
    for (int j = 0; j < 8; ++j) {
      const int d = dc * 8 + j;
      vB[(d >> 4) * 1024 + (row >> 3) * 128 + (d & 15) * 8 + (row & 7)] = (unsigned short)vv[j];
    }
  }
  __syncthreads();

  f32x4 sacc[4] = {};
#pragma unroll
  for (int s = 0; s < 2; ++s) {
    const bf16x8 a = *(const bf16x8*)&qA[wid * 1024 + s * 512 + lane * 8];
#pragma unroll
    for (int c = 0; c < 4; ++c) {
      const bf16x8 bb = *(const bf16x8*)&kB[c * 1024 + s * 512 + lane * 8];
      sacc[c] = __builtin_amdgcn_mfma_f32_16x16x32_bf16(a, bb, sacc[c], 0, 0, 0);
    }
  }

#pragma unroll
  for (int r = 0; r < 4; ++r) {
    const int trow = wid * 16 + lkg * 4 + r;
    float sv[4];
#pragma unroll
    for (int c = 0; c < 4; ++c) {
      const int kp = c * 16 + lrow;
      sv[c] = (kp <= trow && kp < 52) ? sacc[c][r] * 0.125f : -3.0e38f;
    }
    float mx = fmaxf(fmaxf(sv[0], sv[1]), fmaxf(sv[2], sv[3]));
#pragma unroll
    for (int m = 1; m < 16; m <<= 1) mx = fmaxf(mx, __shfl_xor(mx, m));
    float p[4], sum = 0.f;
#pragma unroll
    for (int c = 0; c < 4; ++c) { p[c] = __expf(sv[c] - mx); sum += p[c]; }
#pragma unroll
    for (int m = 1; m < 16; m <<= 1) sum += __shfl_xor(sum, m);
    const float inv = 1.0f / sum;
#pragma unroll
    for (int c = 0; c < 4; ++c) {
      const int kp = c * 16 + lrow;
      pA[wid * 1024 + (kp >> 3) * 128 + (lkg * 4 + r) * 8 + (kp & 7)] = f2bf(p[c] * inv);
    }
  }
  __syncthreads();

  f32x4 oacc[4] = {};
#pragma unroll
  for (int s = 0; s < 2; ++s) {
    const bf16x8 a = *(const bf16x8*)&pA[wid * 1024 + s * 512 + lane * 8];
#pragma unroll
    for (int db = 0; db < 4; ++db) {
      const bf16x8 bb = *(const bf16x8*)&vB[db * 1024 + s * 512 + lane * 8];
      oacc[db] = __builtin_amdgcn_mfma_f32_16x16x32_bf16(a, bb, oacc[db], 0, 0, 0);
    }
  }
#pragma unroll
  for (int db = 0; db < 4; ++db)
#pragma unroll
    for (int r = 0; r < 4; ++r) {
      const int trow = wid * 16 + lkg * 4 + r;
      if (trow < 52) {
        const int d = db * 16 + lrow;
        attno[((size_t)(b * 52 + trow)) * 1024 + h * 64 + d] = f2bf(oacc[db][r]);
      }
    }
}

// ---------- host ----------
extern "C" void kernel_launch(void* const* d_in, const int* in_sizes, int n_in,
                              void* d_out, int out_size, void* d_ws, size_t ws_size,
                              hipStream_t stream) {
  const int*   idx    = (const int*)d_in[0];
  const float* clip   = (const float*)d_in[1];
  const float* tok    = (const float*)d_in[2];
  const float* cond_w = (const float*)d_in[3];
  const float* cond_b = (const float*)d_in[4];
  const float* ln1w   = (const float*)d_in[5];
  const float* ln1b   = (const float*)d_in[6];
  const float* wq     = (const float*)d_in[7];
  const float* bq     = (const float*)d_in[8];
  const float* wk     = (const float*)d_in[9];
  const float* bk     = (const float*)d_in[10];
  const float* wv     = (const float*)d_in[11];
  const float* bv     = (const float*)d_in[12];
  const float* wp     = (const float*)d_in[13];
  const float* bp     = (const float*)d_in[14];
  const float* ln2w   = (const float*)d_in[15];
  const float* ln2b   = (const float*)d_in[16];
  const float* w1     = (const float*)d_in[17];
  const float* b1     = (const float*)d_in[18];
  const float* w2     = (const float*)d_in[19];
  const float* b2     = (const float*)d_in[20];
  const float* lnfw   = (const float*)d_in[21];
  const float* lnfb   = (const float*)d_in[22];
  const float* headw  = (const float*)d_in[23];

  const int M = 6656;
  char* ws = (char*)d_ws;
  size_t off = 0;
  auto alloc = [&](size_t bytes) -> void* {
    void* p = ws + off;
    off += (bytes + 255) & ~(size_t)255;
    return p;
  };

  unsigned short* qkvT  = (unsigned short*)alloc((size_t)8 * 3072 * 1024 * 2);
  unsigned short* wpT   = (unsigned short*)alloc((size_t)8 * 1024 * 1024 * 2);
  unsigned short* w1T   = (unsigned short*)alloc((size_t)8 * 4096 * 1024 * 2);
  unsigned short* w2T   = (unsigned short*)alloc((size_t)8 * 1024 * 4096 * 2);
  unsigned short* headT = (unsigned short*)alloc((size_t)1152 * 1024 * 2);
  float*          qkvB  = (float*)alloc((size_t)8 * 3072 * 4);
  float*          xbuf  = (float*)alloc((size_t)M * 1024 * 4);
  unsigned short* hbuf  = (unsigned short*)alloc((size_t)M * 1024 * 2);
  unsigned short* big   = (unsigned short*)alloc((size_t)M * 4096 * 2);   // qkv | mlp hidden
  unsigned short* attno = (unsigned short*)alloc((size_t)M * 1024 * 2);
  float*          pbuf  = (float*)alloc((size_t)2 * M * 1024 * 4);        // split-K partials
  unsigned short* qkv  = big;
  unsigned short* mlph = big;
  const long ps1024 = (long)M * 1024;

  const dim3 tb(256);
  const dim3 tb512(512);
  transpose_cvt<<<dim3(32, 32, 8), tb, 0, stream>>>(wq, qkvT,                        1024, 1024, 1024, (long)1024 * 1024, (long)3072 * 1024);
  transpose_cvt<<<dim3(32, 32, 8), tb, 0, stream>>>(wk, qkvT + (size_t)1024 * 1024,  1024, 1024, 1024, (long)1024 * 1024, (long)3072 * 1024);
  transpose_cvt<<<dim3(32, 32, 8), tb, 0, stream>>>(wv, qkvT + (size_t)2048 * 1024,  1024, 1024, 1024, (long)1024 * 1024, (long)3072 * 1024);
  transpose_cvt<<<dim3(32, 32, 8), tb, 0, stream>>>(wp, wpT,  1024, 1024, 1024, (long)1024 * 1024, (long)1024 * 1024);
  transpose_cvt<<<dim3(128, 32, 8), tb, 0, stream>>>(w1, w1T, 1024, 4096, 4096, (long)1024 * 4096, (long)4096 * 1024);
  transpose_cvt<<<dim3(32, 128, 8), tb, 0, stream>>>(w2, w2T, 4096, 1024, 1024, (long)4096 * 1024, (long)1024 * 4096);
  transpose_cvt<<<dim3(36, 32, 1), tb, 0, stream>>>(headw, headT, 1024, 1025, 1152, 0, 0);
  concat_bias<<<dim3(96), tb, 0, stream>>>(bq, bk, bv, qkvB);
  embed_kernel<<<dim3(M), tb, 0, stream>>>(idx, clip, tok, cond_w, cond_b, xbuf);
  ln_kernel<<<dim3(M), tb, 0, stream>>>(xbuf, ln1w, ln1b, hbuf);   // layer-0 ln1

  for (int l = 0; l < 8; ++l) {
    // qkv: 26 x 12 = 312 blocks of 256x256 (A-panels small: row-resident traversal)
    gemm256<0><<<dim3(312), tb512, 0, stream>>>(hbuf, qkvT + (size_t)l * 3072 * 1024,
                                                qkvB + l * 3072, qkv, 1024, 3072, 1024, 12, 1, 0);
    attn_kernel<<<dim3(2048), tb, 0, stream>>>(qkv, attno);
    // proj: split-K=2 partials, 208 blocks; col-major (W panel resident, A read-once)
    gemm256<4><<<dim3(208), tb512, 0, stream>>>(attno, wpT + (size_t)l * 1024 * 1024,
                                                nullptr, pbuf, 1024, 1024, 512, 4, 2, 1);
    ln_sum_kernel<<<dim3(M), tb, 0, stream>>>(xbuf, pbuf, ps1024, 2, bp + l * 1024,
                                              ln2w + l * 1024, ln2b + l * 1024, xbuf, hbuf);
    // fc1: 416 blocks (A-panels 0.5MB: row-resident traversal fine)
    gemm256<1><<<dim3(416), tb512, 0, stream>>>(hbuf, w1T + (size_t)l * 4096 * 1024,
                                                b1 + l * 4096, mlph, 1024, 4096, 1024, 16, 1, 0);
    // fc2: split-K=2, 208 blocks; col-major (A-panels 2MB thrash L2 otherwise)
    gemm256<4><<<dim3(208), tb512, 0, stream>>>(mlph, w2T + (size_t)l * 1024 * 4096,
                                                nullptr, pbuf, 4096, 1024, 2048, 4, 2, 1);
    if (l < 7)
      ln_sum_kernel<<<dim3(M), tb, 0, stream>>>(xbuf, pbuf, ps1024, 2, b2 + l * 1024,
                                                ln1w + (l + 1) * 1024, ln1b + (l + 1) * 1024, xbuf, hbuf);
    else
      ln_sum_kernel<<<dim3(M), tb, 0, stream>>>(xbuf, pbuf, ps1024, 2, b2 + l * 1024,
                                                lnfw, lnfb, xbuf, hbuf);
  }
  gemm128<3><<<dim3(52 * 9), tb, 0, stream>>>(hbuf, headT, nullptr, nullptr, d_out, 1024, 1025, 1024, 9, 1);
}

// Round 16
// 2852.844 us; speedup vs baseline: 1.0590x; 1.0590x over previous
//
#include <hip/hip_runtime.h>

using bf16x8 = __attribute__((ext_vector_type(8))) __bf16;
using short8 = __attribute__((ext_vector_type(8))) short;
using u16x8  = __attribute__((ext_vector_type(8))) unsigned short;
using u16x4  = __attribute__((ext_vector_type(4))) unsigned short;
using f32x4  = __attribute__((ext_vector_type(4))) float;

#define DEVI __device__ __forceinline__

// ---------- helpers ----------
DEVI unsigned short f2bf(float f) {
  union { float f; unsigned u; } un; un.f = f;
  unsigned r = un.u + 0x7fffu + ((un.u >> 16) & 1u);   // RNE
  return (unsigned short)(r >> 16);
}
DEVI float bf2f(unsigned short u) {
  union { unsigned u; float f; } x; x.u = (unsigned)u << 16; return x.f;
}

typedef const __attribute__((address_space(1))) void* gas1_t;
typedef __attribute__((address_space(3))) void* las3_t;

DEVI void gload16(const void* g, void* lds) {
  __builtin_amdgcn_global_load_lds(
      reinterpret_cast<gas1_t>(reinterpret_cast<unsigned long long>(g)),
      reinterpret_cast<las3_t>(static_cast<unsigned>(reinterpret_cast<unsigned long long>(lds))),
      16, 0, 0);
}

#define VMW(n) asm volatile("s_waitcnt vmcnt(" #n ")" ::: "memory")
#define LGK0   do { asm volatile("s_waitcnt lgkmcnt(0)" ::: "memory"); __builtin_amdgcn_sched_barrier(0); } while (0)
#define BARS   do { __builtin_amdgcn_s_barrier(); __builtin_amdgcn_sched_barrier(0); } while (0)

// ---------- transpose + f32->bf16 convert:  dst[n][k] = bf16(src[k][n]) ----------
__global__ void __launch_bounds__(256)
transpose_cvt(const float* __restrict__ src, unsigned short* __restrict__ dst,
              int K, int N, int Nrows, long srcStride, long dstStride) {
  src += (size_t)blockIdx.z * srcStride;
  dst += (size_t)blockIdx.z * dstStride;
  __shared__ float tile[32][33];
  const int n0 = blockIdx.x * 32, k0 = blockIdx.y * 32;
  const int tx = threadIdx.x & 31, ty = threadIdx.x >> 5;
#pragma unroll
  for (int i = 0; i < 4; ++i) {
    const int kk = ty + i * 8;
    const int n = n0 + tx;
    tile[kk][tx] = (n < N) ? src[(size_t)(k0 + kk) * N + n] : 0.f;
  }
  __syncthreads();
#pragma unroll
  for (int i = 0; i < 4; ++i) {
    const int nn = ty + i * 8;
    const int n = n0 + nn;
    if (n < Nrows) dst[(size_t)n * K + k0 + tx] = f2bf(tile[tx][nn]);
  }
}

// ---------- concat q/k/v biases per layer into [L][3072] ----------
__global__ void __launch_bounds__(256)
concat_bias(const float* __restrict__ bq, const float* __restrict__ bk,
            const float* __restrict__ bv, float* __restrict__ ob) {
  const int i = blockIdx.x * 256 + threadIdx.x;
  if (i >= 8 * 3072) return;
  const int l = i / 3072, c = i - l * 3072;
  float v;
  if (c < 1024)      v = bq[l * 1024 + c];
  else if (c < 2048) v = bk[l * 1024 + c - 1024];
  else               v = bv[l * 1024 + c - 2048];
  ob[i] = v;
}

// ---------- embedding: cond token + tok_emb gather + sincos PE -> x (f32) ----------
__global__ void __launch_bounds__(256)
embed_kernel(const int* __restrict__ idx, const float* __restrict__ clip,
             const float* __restrict__ tok_emb, const float* __restrict__ cond_w,
             const float* __restrict__ cond_b, float* __restrict__ x) {
  const int row = blockIdx.x;
  const int b = row / 52, t = row - b * 52;
  const int c0 = threadIdx.x * 4;
  float e[4];
  if (t == 0) {
    e[0] = cond_b[c0]; e[1] = cond_b[c0 + 1]; e[2] = cond_b[c0 + 2]; e[3] = cond_b[c0 + 3];
    for (int k = 0; k < 512; ++k) {
      const float cf = clip[b * 512 + k];
      const float4 wv = *(const float4*)&cond_w[k * 1024 + c0];
      e[0] += cf * wv.x; e[1] += cf * wv.y; e[2] += cf * wv.z; e[3] += cf * wv.w;
    }
  } else {
    const int tok = idx[b * 51 + t - 1];
    const float4 tv = *(const float4*)&tok_emb[(size_t)tok * 1024 + c0];
    e[0] = tv.x; e[1] = tv.y; e[2] = tv.z; e[3] = tv.w;
  }
  const float nl = -9.2103403719761836f / 1024.0f;   // -ln(10000)/C
#pragma unroll
  for (int j = 0; j < 4; ++j) {
    const int c = c0 + j;
    const float dv = expf((float)(c & ~1) * nl);
    const float ang = (float)t * dv;
    e[j] += (c & 1) ? cosf(ang) : sinf(ang);
  }
  float4 o; o.x = e[0]; o.y = e[1]; o.z = e[2]; o.w = e[3];
  *(float4*)&x[(size_t)row * 1024 + c0] = o;
}

// ---------- LayerNorm (plain): f32 in -> bf16 out ----------
__global__ void __launch_bounds__(256)
ln_kernel(const float* __restrict__ x, const float* __restrict__ w,
          const float* __restrict__ bsh, unsigned short* __restrict__ out) {
  const size_t row = blockIdx.x;
  const int tid = threadIdx.x;
  const float4 v = *(const float4*)&x[row * 1024 + tid * 4];
  float s1 = v.x + v.y + v.z + v.w;
  float s2 = v.x * v.x + v.y * v.y + v.z * v.z + v.w * v.w;
#pragma unroll
  for (int m = 1; m < 64; m <<= 1) { s1 += __shfl_xor(s1, m); s2 += __shfl_xor(s2, m); }
  __shared__ float red[8];
  const int wid = tid >> 6;
  if ((tid & 63) == 0) { red[wid] = s1; red[4 + wid] = s2; }
  __syncthreads();
  s1 = red[0] + red[1] + red[2] + red[3];
  s2 = red[4] + red[5] + red[6] + red[7];
  const float mean = s1 * (1.0f / 1024.0f);
  const float var  = s2 * (1.0f / 1024.0f) - mean * mean;
  const float rstd = rsqrtf(var + 1e-5f);
  const float4 wv = *(const float4*)&w[tid * 4];
  const float4 bv = *(const float4*)&bsh[tid * 4];
  ushort4 o;
  o.x = f2bf((v.x - mean) * rstd * wv.x + bv.x);
  o.y = f2bf((v.y - mean) * rstd * wv.y + bv.y);
  o.z = f2bf((v.z - mean) * rstd * wv.z + bv.z);
  o.w = f2bf((v.w - mean) * rstd * wv.w + bv.w);
  *(ushort4*)&out[row * 1024 + tid * 4] = o;
}

// ---------- fused residual-reduce + LayerNorm (bf16 partials) ----------
// x_new = x_old + fc_bias + sum_s bf16(partial_s) ; writes x_new (f32) and LN(x_new) (bf16)
__global__ void __launch_bounds__(256)
ln_sum_kernel(const float* __restrict__ xold, const unsigned short* __restrict__ part,
              long pstride, int S, const float* __restrict__ fcb,
              const float* __restrict__ w, const float* __restrict__ bsh,
              float* __restrict__ xnew, unsigned short* __restrict__ hout) {
  const size_t row = blockIdx.x;
  const int tid = threadIdx.x;
  const float4 xv = *(const float4*)&xold[row * 1024 + tid * 4];
  const float4 bb = *(const float4*)&fcb[tid * 4];
  float e0 = xv.x + bb.x, e1 = xv.y + bb.y, e2 = xv.z + bb.z, e3 = xv.w + bb.w;
  for (int s = 0; s < S; ++s) {
    const u16x4 p = *(const u16x4*)&part[(size_t)s * pstride + row * 1024 + tid * 4];
    e0 += bf2f(p[0]); e1 += bf2f(p[1]); e2 += bf2f(p[2]); e3 += bf2f(p[3]);
  }
  float s1 = e0 + e1 + e2 + e3;
  float s2 = e0 * e0 + e1 * e1 + e2 * e2 + e3 * e3;
#pragma unroll
  for (int m = 1; m < 64; m <<= 1) { s1 += __shfl_xor(s1, m); s2 += __shfl_xor(s2, m); }
  __shared__ float red[8];
  const int wid = tid >> 6;
  if ((tid & 63) == 0) { red[wid] = s1; red[4 + wid] = s2; }
  __syncthreads();
  s1 = red[0] + red[1] + red[2] + red[3];
  s2 = red[4] + red[5] + red[6] + red[7];
  const float mean = s1 * (1.0f / 1024.0f);
  const float var  = s2 * (1.0f / 1024.0f) - mean * mean;
  const float rstd = rsqrtf(var + 1e-5f);
  float4 xo; xo.x = e0; xo.y = e1; xo.z = e2; xo.w = e3;
  *(float4*)&xnew[row * 1024 + tid * 4] = xo;
  const float4 wv = *(const float4*)&w[tid * 4];
  const float4 bv = *(const float4*)&bsh[tid * 4];
  ushort4 o;
  o.x = f2bf((e0 - mean) * rstd * wv.x + bv.x);
  o.y = f2bf((e1 - mean) * rstd * wv.y + bv.y);
  o.z = f2bf((e2 - mean) * rstd * wv.z + bv.z);
  o.w = f2bf((e3 - mean) * rstd * wv.w + bv.w);
  *(ushort4*)&hout[row * 1024 + tid * 4] = o;
}

// ---------- 256x256 GEMM, BK=64, 2 x 64 KB dbuf, 2 phases/tile (R12/R14, proven) ----------
// 512 threads (8 waves = 2M x 4N of 128x64). Stage unit U(t,ks) = A+B K-half (32 KB,
// 4 gloads/thread). Per phase: VMW(4) -> barrier -> issue U(t+1,ks) -> 12 ds_read ->
// lgkmcnt(0) -> 32 MFMA. 2 barriers + 2 counted waits per 64 MFMA.
// EPI 0: bf16 out + bias ; 1: + GELU ; 4: bf16 PARTIAL (K-slice z, no bias) --
// all three use the swapped-operand coalesced LDS-staged bf16 epilogue.
template <int EPI>
__global__ void __launch_bounds__(512, 2)
gemm256(const unsigned short* __restrict__ A, const unsigned short* __restrict__ WT,
        const float* __restrict__ bias, void* outp,
        int Kfull, int N, int k_len, int ny, int nz) {
  __shared__ unsigned short smem[65536];                 // 128 KB, reused as C-stage
  const int tid = threadIdx.x;
  const int lane = tid & 63;
  const int wid = tid >> 6;                              // 0..7
  const int lrow = lane & 15, lkg = lane >> 4;
  const int wm = wid >> 2, wn = wid & 3;                 // 2 M-halves x 4 N-quarters

  // bijective XCD chunk swizzle (m204), col-tile fastest within chunk (A-panel reuse)
  const int nwg = gridDim.x;
  int bid = blockIdx.x;
  {
    const int q = nwg >> 3, r = nwg & 7;
    const int xcd = bid & 7, i = bid >> 3;
    bid = ((xcd < r) ? xcd * (q + 1) : r * (q + 1) + (xcd - r) * q) + i;
  }
  const int nxy = nwg / nz;
  const int z = bid / nxy;
  const int rem = bid - z * nxy;
  const int xt = rem / ny;
  const int yt = rem - xt * ny;
  const long m0 = (long)xt * 256;
  const long n0 = (long)yt * 256;
  const int kb = z * k_len;

  // per-thread staging sources: f_j = j*8 + wid, row r = lane&15, kgrp = lane>>4
  const unsigned short* aS[2];
  const unsigned short* bS[2];
#pragma unroll
  for (int j = 0; j < 2; ++j) {
    const int f = j * 8 + wid;
    aS[j] = A  + (m0 + f * 16 + lrow) * (long)Kfull + kb + lkg * 8;
    bS[j] = WT + (n0 + f * 16 + lrow) * (long)Kfull + kb + lkg * 8;
  }

  auto STU = [&](int t, int ks) {                        // one K-half of tile t (4 gloads)
    const int bo = (t & 1) * 32768;
    const long kt = (long)t * 64 + ks * 32;
    gload16(aS[0] + kt, smem + bo + ks * 8192 + wid * 512);
    gload16(aS[1] + kt, smem + bo + ks * 8192 + (8 + wid) * 512);
    gload16(bS[0] + kt, smem + bo + 16384 + ks * 8192 + wid * 512);
    gload16(bS[1] + kt, smem + bo + 16384 + ks * 8192 + (8 + wid) * 512);
  };

  f32x4 acc[8][4] = {};
  const int T = k_len >> 6;                              // k_len multiple of 64

  STU(0, 0); STU(0, 1);                                  // 8 gloads in flight

  for (int t = 0; t < T; ++t) {
    const int bo = (t & 1) * 32768;
    bf16x8 afr[8], bfr[4];
#pragma unroll
    for (int ks = 0; ks < 2; ++ks) {
      if (t + 1 < T || ks == 0) VMW(4);                  // own U(t,ks) loads done
      else                      VMW(0);                  // final half: drain
      BARS;                                              // all waves' U(t,ks) writes visible
      if (t + 1 < T) STU(t + 1, ks);                     // other buffer, readers done at t-1
#pragma unroll
      for (int m = 0; m < 8; ++m)
        afr[m] = *(const bf16x8*)&smem[bo + ks * 8192 + (wm * 8 + m) * 512 + lane * 8];
#pragma unroll
      for (int n = 0; n < 4; ++n)
        bfr[n] = *(const bf16x8*)&smem[bo + 16384 + ks * 8192 + (wn * 4 + n) * 512 + lane * 8];
      LGK0;
      __builtin_amdgcn_s_setprio(1);
#pragma unroll
      for (int m = 0; m < 8; ++m)
#pragma unroll
        for (int n = 0; n < 4; ++n)
          acc[m][n] = __builtin_amdgcn_mfma_f32_16x16x32_bf16(bfr[n], afr[m], acc[m][n], 0, 0, 0);
      __builtin_amdgcn_s_setprio(0);
    }
  }
  __syncthreads();                                       // protect smem reuse as C-stage

  // swapped operands: lane holds C[row = wm*128 + m*16 + lrow][cols = wn*64 + n*16 + lkg*4 .. +3]
#pragma unroll
  for (int m = 0; m < 8; ++m) {
    const int row = wm * 128 + m * 16 + lrow;
    const unsigned rb = (unsigned)row * 512;
    const unsigned sw = (unsigned)(row & 7) << 4;
#pragma unroll
    for (int n = 0; n < 4; ++n) {
      const int colb = wn * 64 + n * 16 + lkg * 4;
      float4 bv = { 0.f, 0.f, 0.f, 0.f };
      if constexpr (EPI != 4) bv = *(const float4*)&bias[n0 + colb];
      float v0 = acc[m][n][0] + bv.x;
      float v1 = acc[m][n][1] + bv.y;
      float v2 = acc[m][n][2] + bv.z;
      float v3 = acc[m][n][3] + bv.w;
      if constexpr (EPI == 1) {
        v0 = 0.5f * v0 * (1.0f + erff(v0 * 0.70710678118654752f));
        v1 = 0.5f * v1 * (1.0f + erff(v1 * 0.70710678118654752f));
        v2 = 0.5f * v2 * (1.0f + erff(v2 * 0.70710678118654752f));
        v3 = 0.5f * v3 * (1.0f + erff(v3 * 0.70710678118654752f));
      }
      u16x4 o = { f2bf(v0), f2bf(v1), f2bf(v2), f2bf(v3) };
      *(u16x4*)((char*)smem + ((rb + colb * 2) ^ sw)) = o;
    }
  }
  __syncthreads();
  unsigned short* out = (unsigned short*)outp;
  if constexpr (EPI == 4) out += (size_t)z * ((size_t)(nxy / ny) * 256) * N;
#pragma unroll
  for (int i = 0; i < 16; ++i) {
    const int idx = tid + i * 512;        // 16B chunk, 8192 total (256 rows x 32)
    const int row = idx >> 5, c32 = idx & 31;
    const unsigned byteoff = ((unsigned)row * 512 + (unsigned)c32 * 16) ^ ((unsigned)(row & 7) << 4);
    const u16x8 v = *(const u16x8*)((const char*)smem + byteoff);
    *(u16x8*)&out[(m0 + row) * (long)N + n0 + c32 * 8] = v;
  }
}

// ---------- 128x128 GEMM (3 buffers, 48KB, depth-2) for the head ----------
// EPI 3: f32 out plain
template <int EPI>
__global__ void __launch_bounds__(256)
gemm128(const unsigned short* __restrict__ A, const unsigned short* __restrict__ WT,
        const float* __restrict__ bias, const float* res, void* outp,
        int Kfull, int N, int k_len, int ny, int nz) {
  __shared__ unsigned short smem[24576];                 // 48 KB
  const int tid = threadIdx.x;
  const int lane = tid & 63;
  const int wid = tid >> 6;
  const int lrow = lane & 15, lkg = lane >> 4;
  const int wr = wid >> 1, wc = wid & 1;

  const int nwg = gridDim.x;
  int bid = blockIdx.x;
  {
    const int q = nwg >> 3, r = nwg & 7;
    const int xcd = bid & 7, i = bid >> 3;
    bid = ((xcd < r) ? xcd * (q + 1) : r * (q + 1) + (xcd - r) * q) + i;
  }
  const int nxy = nwg / nz;
  const int z = bid / nxy;
  const int rem = bid - z * nxy;
  const int xt = rem / ny;
  const int yt = rem - xt * ny;
  const long m0 = (long)xt * 128;
  const long n0 = (long)yt * 128;
  const int kb = z * k_len;

  const unsigned short* a0 = A + (m0 + (wid * 2 + 0) * 16 + lrow) * (long)Kfull + kb + lkg * 8;
  const unsigned short* a1 = A + (m0 + (wid * 2 + 1) * 16 + lrow) * (long)Kfull + kb + lkg * 8;
  const unsigned short* b0 = WT + (n0 + (wid * 2 + 0) * 16 + lrow) * (long)Kfull + kb + lkg * 8;
  const unsigned short* b1 = WT + (n0 + (wid * 2 + 1) * 16 + lrow) * (long)Kfull + kb + lkg * 8;
  const int so0 = (wid * 2 + 0) * 512, so1 = (wid * 2 + 1) * 512;

  f32x4 acc[4][4] = {};
  const int T = k_len >> 5;

  auto STAGE = [&](int t) {
    const int boff = (t % 3) * 8192;
    const int kt = t * 32;
    gload16(a0 + kt, smem + boff + so0);
    gload16(a1 + kt, smem + boff + so1);
    gload16(b0 + kt, smem + boff + 4096 + so0);
    gload16(b1 + kt, smem + boff + 4096 + so1);
  };

  STAGE(0);
  STAGE(1);

  for (int t = 0; t < T; ++t) {
    if (t + 1 < T) asm volatile("s_waitcnt vmcnt(4)" ::: "memory");
    else           asm volatile("s_waitcnt vmcnt(0)" ::: "memory");
    __builtin_amdgcn_s_barrier();
    __builtin_amdgcn_sched_barrier(0);
    if (t + 2 < T) STAGE(t + 2);
    const int cb = (t % 3) * 8192;
    bf16x8 af[4], bf8[4];
#pragma unroll
    for (int m = 0; m < 4; ++m) af[m] = *(const bf16x8*)&smem[cb + (wr * 4 + m) * 512 + lane * 8];
#pragma unroll
    for (int n = 0; n < 4; ++n) bf8[n] = *(const bf16x8*)&smem[cb + 4096 + (wc * 4 + n) * 512 + lane * 8];
#pragma unroll
    for (int m = 0; m < 4; ++m)
#pragma unroll
      for (int n = 0; n < 4; ++n)
        acc[m][n] = __builtin_amdgcn_mfma_f32_16x16x32_bf16(af[m], bf8[n], acc[m][n], 0, 0, 0);
  }
  __syncthreads();

#pragma unroll
  for (int n = 0; n < 4; ++n) {
    const int col = (int)n0 + wc * 64 + n * 16 + lrow;
    const bool cv = col < N;
#pragma unroll
    for (int m = 0; m < 4; ++m) {
      const long rowb = m0 + wr * 64 + m * 16 + lkg * 4;
#pragma unroll
      for (int r = 0; r < 4; ++r) {
        if (cv) ((float*)outp)[(rowb + r) * (long)N + col] = acc[m][n][r];
      }
    }
  }
}

// ---------- fused causal attention, one block per (b, h) ----------
__global__ void __launch_bounds__(256)
attn_kernel(const unsigned short* __restrict__ qkv,   // [M][3072] bf16 (q|k|v)
            unsigned short* __restrict__ attno) {     // [M][1024] bf16
  __shared__ unsigned short qA[4096];
  __shared__ unsigned short kB[4096];
  __shared__ unsigned short vB[4096];
  __shared__ unsigned short pA[4096];
  const int bh = blockIdx.x;
  const int b = bh >> 4, h = bh & 15;
  const int tid = threadIdx.x;
  const int lane = tid & 63;
  const int wid = tid >> 6;
  const int lrow = lane & 15, lkg = lane >> 4;

  for (int i = tid; i < 512; i += 256) {
    const int row = i >> 3;
    const int dc = i & 7;
    short8 qv = {}, kv = {}, vv = {};
    if (row < 52) {
      const unsigned short* base = qkv + ((size_t)(b * 52 + row)) * 3072 + h * 64 + dc * 8;
      qv = *(const short8*)(base);
      kv = *(const short8*)(base + 1024);
      vv = *(const short8*)(base + 2048);
    }
    *(short8*)&qA[(row >> 4) * 1024 + dc * 128 + (row & 15) * 8] = qv;
    *(short8*)&kB[(row >> 4) * 1024 + dc * 128 + (row & 15) * 8] = kv;
#pragma unroll
    for (int j = 0; j < 8; ++j) {
      const int d = dc * 8 + j;
      vB[(d >> 4) * 1024 + (row >> 3) * 128 + (d & 15) * 8 + (row & 7)] = (unsigned short)vv[j];
    }
  }
  __syncthreads();

  f32x4 sacc[4] = {};
#pragma unroll
  for (int s = 0; s < 2; ++s) {
    const bf16x8 a = *(const bf16x8*)&qA[wid * 1024 + s * 512 + lane * 8];
#pragma unroll
    for (int c = 0; c < 4; ++c) {
      const bf16x8 bb = *(const bf16x8*)&kB[c * 1024 + s * 512 + lane * 8];
      sacc[c] = __builtin_amdgcn_mfma_f32_16x16x32_bf16(a, bb, sacc[c], 0, 0, 0);
    }
  }

#pragma unroll
  for (int r = 0; r < 4; ++r) {
    const int trow = wid * 16 + lkg * 4 + r;
    float sv[4];
#pragma unroll
    for (int c = 0; c < 4; ++c) {
      const int kp = c * 16 + lrow;
      sv[c] = (kp <= trow && kp < 52) ? sacc[c][r] * 0.125f : -3.0e38f;
    }
    float mx = fmaxf(fmaxf(sv[0], sv[1]), fmaxf(sv[2], sv[3]));
#pragma unroll
    for (int m = 1; m < 16; m <<= 1) mx = fmaxf(mx, __shfl_xor(mx, m));
    float p[4], sum = 0.f;
#pragma unroll
    for (int c = 0; c < 4; ++c) { p[c] = __expf(sv[c] - mx); sum += p[c]; }
#pragma unroll
    for (int m = 1; m < 16; m <<= 1) sum += __shfl_xor(sum, m);
    const float inv = 1.0f / sum;
#pragma unroll
    for (int c = 0; c < 4; ++c) {
      const int kp = c * 16 + lrow;
      pA[wid * 1024 + (kp >> 3) * 128 + (lkg * 4 + r) * 8 + (kp & 7)] = f2bf(p[c] * inv);
    }
  }
  __syncthreads();

  f32x4 oacc[4] = {};
#pragma unroll
  for (int s = 0; s < 2; ++s) {
    const bf16x8 a = *(const bf16x8*)&pA[wid * 1024 + s * 512 + lane * 8];
#pragma unroll
    for (int db = 0; db < 4; ++db) {
      const bf16x8 bb = *(const bf16x8*)&vB[db * 1024 + s * 512 + lane * 8];
      oacc[db] = __builtin_amdgcn_mfma_f32_16x16x32_bf16(a, bb, oacc[db], 0, 0, 0);
    }
  }
#pragma unroll
  for (int db = 0; db < 4; ++db)
#pragma unroll
    for (int r = 0; r < 4; ++r) {
      const int trow = wid * 16 + lkg * 4 + r;
      if (trow < 52) {
        const int d = db * 16 + lrow;
        attno[((size_t)(b * 52 + trow)) * 1024 + h * 64 + d] = f2bf(oacc[db][r]);
      }
    }
}

// ---------- host ----------
extern "C" void kernel_launch(void* const* d_in, const int* in_sizes, int n_in,
                              void* d_out, int out_size, void* d_ws, size_t ws_size,
                              hipStream_t stream) {
  const int*   idx    = (const int*)d_in[0];
  const float* clip   = (const float*)d_in[1];
  const float* tok    = (const float*)d_in[2];
  const float* cond_w = (const float*)d_in[3];
  const float* cond_b = (const float*)d_in[4];
  const float* ln1w   = (const float*)d_in[5];
  const float* ln1b   = (const float*)d_in[6];
  const float* wq     = (const float*)d_in[7];
  const float* bq     = (const float*)d_in[8];
  const float* wk     = (const float*)d_in[9];
  const float* bk     = (const float*)d_in[10];
  const float* wv     = (const float*)d_in[11];
  const float* bv     = (const float*)d_in[12];
  const float* wp     = (const float*)d_in[13];
  const float* bp     = (const float*)d_in[14];
  const float* ln2w   = (const float*)d_in[15];
  const float* ln2b   = (const float*)d_in[16];
  const float* w1     = (const float*)d_in[17];
  const float* b1     = (const float*)d_in[18];
  const float* w2     = (const float*)d_in[19];
  const float* b2     = (const float*)d_in[20];
  const float* lnfw   = (const float*)d_in[21];
  const float* lnfb   = (const float*)d_in[22];
  const float* headw  = (const float*)d_in[23];

  const int M = 6656;
  char* ws = (char*)d_ws;
  size_t off = 0;
  auto alloc = [&](size_t bytes) -> void* {
    void* p = ws + off;
    off += (bytes + 255) & ~(size_t)255;
    return p;
  };

  unsigned short* qkvT  = (unsigned short*)alloc((size_t)8 * 3072 * 1024 * 2);
  unsigned short* wpT   = (unsigned short*)alloc((size_t)8 * 1024 * 1024 * 2);
  unsigned short* w1T   = (unsigned short*)alloc((size_t)8 * 4096 * 1024 * 2);
  unsigned short* w2T   = (unsigned short*)alloc((size_t)8 * 1024 * 4096 * 2);
  unsigned short* headT = (unsigned short*)alloc((size_t)1152 * 1024 * 2);
  float*          qkvB  = (float*)alloc((size_t)8 * 3072 * 4);
  float*          xbuf  = (float*)alloc((size_t)M * 1024 * 4);
  unsigned short* hbuf  = (unsigned short*)alloc((size_t)M * 1024 * 2);
  unsigned short* big   = (unsigned short*)alloc((size_t)M * 4096 * 2);   // qkv | mlp hidden
  unsigned short* attno = (unsigned short*)alloc((size_t)M * 1024 * 2);
  unsigned short* pbuf  = (unsigned short*)alloc((size_t)2 * M * 1024 * 2); // bf16 split-K partials
  unsigned short* qkv  = big;
  unsigned short* mlph = big;
  const long ps1024 = (long)M * 1024;

  const dim3 tb(256);
  const dim3 tb512(512);
  transpose_cvt<<<dim3(32, 32, 8), tb, 0, stream>>>(wq, qkvT,                        1024, 1024, 1024, (long)1024 * 1024, (long)3072 * 1024);
  transpose_cvt<<<dim3(32, 32, 8), tb, 0, stream>>>(wk, qkvT + (size_t)1024 * 1024,  1024, 1024, 1024, (long)1024 * 1024, (long)3072 * 1024);
  transpose_cvt<<<dim3(32, 32, 8), tb, 0, stream>>>(wv, qkvT + (size_t)2048 * 1024,  1024, 1024, 1024, (long)1024 * 1024, (long)3072 * 1024);
  transpose_cvt<<<dim3(32, 32, 8), tb, 0, stream>>>(wp, wpT,  1024, 1024, 1024, (long)1024 * 1024, (long)1024 * 1024);
  transpose_cvt<<<dim3(128, 32, 8), tb, 0, stream>>>(w1, w1T, 1024, 4096, 4096, (long)1024 * 4096, (long)4096 * 1024);
  transpose_cvt<<<dim3(32, 128, 8), tb, 0, stream>>>(w2, w2T, 4096, 1024, 1024, (long)4096 * 1024, (long)1024 * 4096);
  transpose_cvt<<<dim3(36, 32, 1), tb, 0, stream>>>(headw, headT, 1024, 1025, 1152, 0, 0);
  concat_bias<<<dim3(96), tb, 0, stream>>>(bq, bk, bv, qkvB);
  embed_kernel<<<dim3(M), tb, 0, stream>>>(idx, clip, tok, cond_w, cond_b, xbuf);
  ln_kernel<<<dim3(M), tb, 0, stream>>>(xbuf, ln1w, ln1b, hbuf);   // layer-0 ln1

  for (int l = 0; l < 8; ++l) {
    // qkv: 26 x 12 = 312 blocks of 256x256
    gemm256<0><<<dim3(312), tb512, 0, stream>>>(hbuf, qkvT + (size_t)l * 3072 * 1024,
                                                qkvB + l * 3072, qkv, 1024, 3072, 1024, 12, 1);
    attn_kernel<<<dim3(2048), tb, 0, stream>>>(qkv, attno);
    // proj: split-K=2 bf16 partials, 208 blocks; reduce+residual+ln2 fused
    gemm256<4><<<dim3(208), tb512, 0, stream>>>(attno, wpT + (size_t)l * 1024 * 1024,
                                                nullptr, pbuf, 1024, 1024, 512, 4, 2);
    ln_sum_kernel<<<dim3(M), tb, 0, stream>>>(xbuf, pbuf, ps1024, 2, bp + l * 1024,
                                              ln2w + l * 1024, ln2b + l * 1024, xbuf, hbuf);
    // fc1: 416 blocks
    gemm256<1><<<dim3(416), tb512, 0, stream>>>(hbuf, w1T + (size_t)l * 4096 * 1024,
                                                b1 + l * 4096, mlph, 1024, 4096, 1024, 16, 1);
    // fc2: split-K=2 bf16 partials, 208 blocks; reduce fused into next ln1 (or lnf)
    gemm256<4><<<dim3(208), tb512, 0, stream>>>(mlph, w2T + (size_t)l * 1024 * 4096,
                                                nullptr, pbuf, 4096, 1024, 2048, 4, 2);
    if (l < 7)
      ln_sum_kernel<<<dim3(M), tb, 0, stream>>>(xbuf, pbuf, ps1024, 2, b2 + l * 1024,
                                                ln1w + (l + 1) * 1024, ln1b + (l + 1) * 1024, xbuf, hbuf);
    else
      ln_sum_kernel<<<dim3(M), tb, 0, stream>>>(xbuf, pbuf, ps1024, 2, b2 + l * 1024,
                                                lnfw, lnfb, xbuf, hbuf);
  }
  gemm128<3><<<dim3(52 * 9), tb, 0, stream>>>(hbuf, headT, nullptr, nullptr, d_out, 1024, 1025, 1024, 9, 1);
}